// Round 5
// baseline (250.447 us; speedup 1.0000x reference)
//
#include <hip/hip_runtime.h>
#include <math.h>

#define NUM_IN 1024
#define TILE_R 16
#define NB_MAX 256
#define TILE_BYTES (TILE_R * NUM_IN * 4)

using bf16x8 = __attribute__((ext_vector_type(8))) short;
using f32x4  = __attribute__((ext_vector_type(4))) float;

typedef __attribute__((address_space(1))) const void gvoid_t;
typedef __attribute__((address_space(3))) void lvoid_t;

__device__ __forceinline__ unsigned int f2bf1(float f) {
  unsigned int u = __float_as_uint(f);
  return (u + 0x7fffu + ((u >> 16) & 1u)) >> 16;   // RNE f32 -> bf16
}
__device__ __forceinline__ unsigned int pk2(float a, float b) {
  return f2bf1(a) | (f2bf1(b) << 16);
}
__device__ __forceinline__ float bf2f(unsigned int s) {
  return __uint_as_float(s << 16);
}

// barrier draining LDS ops only — DMA traffic stays in flight
#define BARX() do { \
  __builtin_amdgcn_sched_barrier(0); \
  asm volatile("s_waitcnt lgkmcnt(0)" ::: "memory"); \
  __builtin_amdgcn_s_barrier(); \
  __builtin_amdgcn_sched_barrier(0); \
} while (0)

#define WAIT_VM(n) do { \
  __builtin_amdgcn_sched_barrier(0); \
  asm volatile("s_waitcnt vmcnt(" #n ")" ::: "memory"); \
  __builtin_amdgcn_sched_barrier(0); \
} while (0)

// 256 blocks x 512 threads (8 waves). Wave w: n-tile nt=w&3, K-half kh=w>>2.
// 3-tile pipeline: compute T (xt[cur]) | convert T+1 (fstg -> xt[cur^1]) |
// DMA T+2 -> fstg. Counted vmcnt(4): per-wave VMEM queue never empties.
__global__ __launch_bounds__(512, 1) void ga_main(
    const float* __restrict__ x,
    const float* __restrict__ Vw, const float* __restrict__ Uw,
    const float* __restrict__ Vb, const float* __restrict__ Ub,
    const float* __restrict__ ww, const float* __restrict__ wb,
    float* __restrict__ wsAcc, float* __restrict__ wsM, float* __restrict__ wsS,
    int nb, int nTiles)
{
  __shared__ __align__(16) unsigned short xt[2][TILE_R * NUM_IN]; // 64 KB bf16 dbuf (XOR-swizzled)
  __shared__ __align__(16) float fstg[TILE_R * NUM_IN];           // 64 KB f32 DMA landing (linear)
  __shared__ __align__(16) float prered[TILE_R][2][64];           // 8 KB
  __shared__ __align__(16) float lgs[TILE_R];

  const int tid = threadIdx.x;
  const int b   = blockIdx.x;
  const int w   = tid >> 6;
  const int l   = tid & 63;
  const int l15 = l & 15;
  const int kg  = l >> 4;
  const int nt  = w & 3;
  const int kh  = w >> 2;
  const int h   = tid & 31;
  const int rr  = tid >> 5;

  const float vbh = Vb[h], ubh = Ub[h], wwh = ww[h];
  const float wb0 = wb[0];

  // ---- weights: bf16 B-fragments, 16 x uint4 = 64 VGPR, loaded once ----
  uint4 bfr[16];
  {
    const int o = (nt << 4) + l15;
    const float* Wr = (o < 32) ? (Vw + (size_t)o * NUM_IN) : (Uw + (size_t)(o - 32) * NUM_IN);
    #pragma unroll
    for (int s = 0; s < 16; ++s) {
      const int k0 = (kh << 9) + (s << 5) + (kg << 3);
      const float4 a = *reinterpret_cast<const float4*>(Wr + k0);
      const float4 c = *reinterpret_cast<const float4*>(Wr + k0 + 4);
      uint4 v;
      v.x = pk2(a.x, a.y); v.y = pk2(a.z, a.w);
      v.z = pk2(c.x, c.y); v.w = pk2(c.z, c.w);
      bfr[s] = v;
    }
    #pragma unroll
    for (int s = 0; s < 16; ++s)   // 32-bit tied anchors (128-bit "+v" unsupported)
      asm volatile("" : "+v"(bfr[s].x), "+v"(bfr[s].y), "+v"(bfr[s].z), "+v"(bfr[s].w));
  }

  const char* xbytes = (const char*)x;
  char* fstgb = (char*)fstg;
  const f32x4* fs = (const f32x4*)fstg;

  float M = -INFINITY, S = 0.f;
  float aX = 0.f, aY = 0.f;
  const int cb = (w << 8) + (l << 2);    // Phase-B byte col base
  int cur = 0;
  int T = b;

  // DMA one 4 KB half (row) of this wave's region for tile Tt, half hf in {0,1}
  #define ISSUE_HALF(Tt, hf) do { \
    __builtin_amdgcn_sched_barrier(0); \
    const char* gsrc_ = xbytes + (size_t)(Tt) * TILE_BYTES + (w << 13) + ((hf) << 12) + (l << 4); \
    char* ldst_ = fstgb + (w << 13) + ((hf) << 12); \
    __builtin_amdgcn_global_load_lds((gvoid_t*)(gsrc_),          (lvoid_t*)(ldst_),          16, 0, 0); \
    __builtin_amdgcn_global_load_lds((gvoid_t*)(gsrc_ + 1024),   (lvoid_t*)(ldst_ + 1024),   16, 0, 0); \
    __builtin_amdgcn_global_load_lds((gvoid_t*)(gsrc_ + 2048),   (lvoid_t*)(ldst_ + 2048),   16, 0, 0); \
    __builtin_amdgcn_global_load_lds((gvoid_t*)(gsrc_ + 3072),   (lvoid_t*)(ldst_ + 3072),   16, 0, 0); \
    __builtin_amdgcn_sched_barrier(0); \
  } while (0)

  // convert one row (4 KB f32 -> 2 KB swizzled bf16) into xt buffer xb_
  #define CONV_ROW(xb_, row_) do { \
    _Pragma("unroll") \
    for (int j = 0; j < 4; ++j) { \
      const int q = ((row_) << 8) + (j << 6) + l; \
      const f32x4 f = fs[q]; \
      uint2 v; v.x = pk2(f[0], f[1]); v.y = pk2(f[2], f[3]); \
      *reinterpret_cast<uint2*>((xb_) + (((q << 3)) ^ (((row_) & 7) << 4))) = v; \
    } \
  } while (0)

  const int rowA = (w << 1), rowB = (w << 1) + 1;

  // ---- prologue: DMA tile b, convert -> xt[0], prime queue with tile b+nb ----
  ISSUE_HALF(T, 0);
  ISSUE_HALF(T, 1);
  WAIT_VM(0);
  { char* xb = (char*)xt[0]; CONV_ROW(xb, rowA); CONV_ROW(xb, rowB); }
  if (T + nb < nTiles) { ISSUE_HALF(T + nb, 0); ISSUE_HALF(T + nb, 1); }
  BARX();

  while (true) {
    const bool more1 = (T + nb)     < nTiles;   // tile T+nb in flight (queue==8)
    const bool more2 = (T + 2 * nb) < nTiles;

    // ---- convert T+1 (half-granular), issue T+2; queue never below 4 ----
    if (more1) {
      char* xb = (char*)xt[cur ^ 1];
      WAIT_VM(4);                    // half A of T+1 landed
      CONV_ROW(xb, rowA);
      if (more2) ISSUE_HALF(T + 2 * nb, 0);
      WAIT_VM(4);                    // half B of T+1 landed (oldest 4 of queue)
      CONV_ROW(xb, rowB);
      if (more2) ISSUE_HALF(T + 2 * nb, 1);
    }

    // ---- MFMA: partial logits for this wave's (nt, kh) on tile T ----
    {
      f32x4 acc = {0.f, 0.f, 0.f, 0.f};
      const char* xb = (const char*)xt[cur];
      #pragma unroll
      for (int s = 0; s < 16; ++s) {
        const int aoff = (l15 << 11) + ((((kh << 10) + (s << 6) + (kg << 4))) ^ ((l15 & 7) << 4));
        const bf16x8 af = *reinterpret_cast<const bf16x8*>(xb + aoff);
        acc = __builtin_amdgcn_mfma_f32_16x16x32_bf16(af, __builtin_bit_cast(bf16x8, bfr[s]), acc, 0, 0, 0);
      }
      #pragma unroll
      for (int r = 0; r < 4; ++r)
        prered[(kg << 2) + r][kh][(nt << 4) + l15] = acc[r];   // C/D: row=(l>>4)*4+r, col=l15
    }
    BARX();

    // ---- activations + per-row logit (512 threads = 16 rows x 32 h) ----
    {
      const float pv = prered[rr][0][h] + prered[rr][1][h] + vbh;
      const float pu = prered[rr][0][32 + h] + prered[rr][1][32 + h] + ubh;
      const float av = tanhf(pv);
      const float au = 1.f / (1.f + __expf(-pu));
      float g = av * au * wwh;
      g += __shfl_xor(g, 1);
      g += __shfl_xor(g, 2);
      g += __shfl_xor(g, 4);
      g += __shfl_xor(g, 8);
      g += __shfl_xor(g, 16);
      if (h == 0) lgs[rr] = g + wb0;
    }
    BARX();

    // ---- Phase B: online softmax + weighted accumulation (2 cols/thread) ----
    {
      const f32x4* lgv = (const f32x4*)lgs;
      float lf[16];
      #pragma unroll
      for (int p4 = 0; p4 < 4; ++p4) {
        const f32x4 v = lgv[p4];
        lf[p4*4+0] = v[0]; lf[p4*4+1] = v[1]; lf[p4*4+2] = v[2]; lf[p4*4+3] = v[3];
      }
      float mc = lf[0];
      #pragma unroll
      for (int r = 1; r < 16; ++r) mc = fmaxf(mc, lf[r]);
      const float newM = fmaxf(M, mc);
      const float scale = __expf(M - newM);
      S *= scale; aX *= scale; aY *= scale;
      const char* xb = (const char*)xt[cur];
      #pragma unroll
      for (int r = 0; r < 16; ++r) {
        const float p = __expf(lf[r] - newM);
        S += p;
        const unsigned int xv = *reinterpret_cast<const unsigned int*>(
            xb + (r << 11) + (cb ^ ((r & 7) << 4)));
        aX += p * bf2f(xv & 0xffffu);
        aY += p * bf2f(xv >> 16);
      }
      M = newM;
    }
    BARX();   // publishes this iteration's converts; frees xt[cur] for reuse

    if (!more1) break;
    cur ^= 1;
    T += nb;
  }

  float2* dst = reinterpret_cast<float2*>(&wsAcc[(size_t)b * NUM_IN + (w << 7) + (l << 1)]);
  *dst = make_float2(aX, aY);
  if (tid == 0) { wsM[b] = M; wsS[b] = S; }
}

__global__ void ga_combine(const float* __restrict__ wsAcc, const float* __restrict__ wsM,
                           const float* __restrict__ wsS, float* __restrict__ out, int nb)
{
  const int e = blockIdx.x * blockDim.x + threadIdx.x;
  if (e >= NUM_IN) return;
  float M = -INFINITY;
  for (int i = 0; i < nb; ++i) M = fmaxf(M, wsM[i]);
  float S = 0.f, m = 0.f;
  for (int i = 0; i < nb; ++i) {
    const float wg = __expf(wsM[i] - M);
    S += wg * wsS[i];
    m = fmaf(wg, wsAcc[(size_t)i * NUM_IN + e], m);
  }
  out[e] = m / S;
}

extern "C" void kernel_launch(void* const* d_in, const int* in_sizes, int n_in,
                              void* d_out, int out_size, void* d_ws, size_t ws_size,
                              hipStream_t stream)
{
  const float* x  = (const float*)d_in[0];
  const float* Vw = (const float*)d_in[1];
  const float* Vb = (const float*)d_in[2];
  const float* Uw = (const float*)d_in[3];
  const float* Ub = (const float*)d_in[4];
  const float* ww = (const float*)d_in[5];
  const float* wb = (const float*)d_in[6];
  float* out = (float*)d_out;

  const int Nrows  = in_sizes[0] / NUM_IN;   // 200000
  const int nTiles = Nrows / TILE_R;         // 12500

  const size_t per = (size_t)NUM_IN * 4 + 8;
  int nb = (int)(ws_size / per);
  if (nb > NB_MAX)  nb = NB_MAX;
  if (nb > nTiles)  nb = nTiles;
  if (nb < 1)       nb = 1;

  float* wsAcc = (float*)d_ws;
  float* wsM   = wsAcc + (size_t)nb * NUM_IN;
  float* wsS   = wsM + nb;

  ga_main<<<nb, 512, 0, stream>>>(x, Vw, Uw, Vb, Ub, ww, wb, wsAcc, wsM, wsS, nb, nTiles);
  ga_combine<<<4, 256, 0, stream>>>(wsAcc, wsM, wsS, out, nb);
}

// Round 6
// 243.243 us; speedup vs baseline: 1.0296x; 1.0296x over previous
//
#include <hip/hip_runtime.h>
#include <math.h>

#define NUM_IN 1024
#define TILE_R 16
#define NB_MAX 256
#define T4 (TILE_R * NUM_IN / 4)   // 4096 float4 per tile

using bf16x8 = __attribute__((ext_vector_type(8))) short;
using f32x4  = __attribute__((ext_vector_type(4))) float;

__device__ __forceinline__ unsigned int f2bf1(float f) {
  unsigned int u = __float_as_uint(f);
  return (u + 0x7fffu + ((u >> 16) & 1u)) >> 16;   // RNE f32 -> bf16
}
__device__ __forceinline__ unsigned int pk2(float a, float b) {
  return f2bf1(a) | (f2bf1(b) << 16);
}
__device__ __forceinline__ float bf2f(unsigned int s) {
  return __uint_as_float(s << 16);
}

// barrier draining LDS ops only — global loads stay in flight
#define BARX() do { \
  __builtin_amdgcn_sched_barrier(0); \
  asm volatile("s_waitcnt lgkmcnt(0)" ::: "memory"); \
  __builtin_amdgcn_s_barrier(); \
  __builtin_amdgcn_sched_barrier(0); \
} while (0)

#define WAIT_VM0() do { \
  __builtin_amdgcn_sched_barrier(0); \
  asm volatile("s_waitcnt vmcnt(0)" ::: "memory"); \
  __builtin_amdgcn_sched_barrier(0); \
} while (0)

// 256 blocks x 1024 threads (16 waves, 4/SIMD). Wave w: nt=w&3, K-quarter kq=w>>2.
// Register staging (T14): tile T+2's loads issued mid-iteration T, drained
// mid-iteration T+1 -> ~4 KB/wave outstanding across the whole iteration.
__global__ __launch_bounds__(1024, 4) void ga_main(
    const float* __restrict__ x,
    const float* __restrict__ Vw, const float* __restrict__ Uw,
    const float* __restrict__ Vb, const float* __restrict__ Ub,
    const float* __restrict__ ww, const float* __restrict__ wb,
    float* __restrict__ wsAcc, float* __restrict__ wsM, float* __restrict__ wsS,
    int nb, int nTiles)
{
  __shared__ __align__(16) unsigned short xt[2][TILE_R * NUM_IN]; // 64 KB bf16 dbuf (XOR-swizzled)
  __shared__ __align__(16) float prered[TILE_R][4][64];           // 16 KB (reused as merge buf)
  __shared__ __align__(16) float lgs[TILE_R];

  const int tid = threadIdx.x;
  const int b   = blockIdx.x;
  const int w   = tid >> 6;
  const int l   = tid & 63;
  const int l15 = l & 15;
  const int kg  = l >> 4;
  const int nt  = w & 3;
  const int kq  = w >> 2;        // K-quarter 0..3
  const int h   = tid & 31;
  const int rr  = tid >> 5;      // row, valid for tid<512
  const int c2  = tid & 511;     // column pair for Phase B
  const int hf  = tid >> 9;      // row-half 0/1
  const int r0  = hf << 3;

  float vbh = 0.f, ubh = 0.f, wwh = 0.f;
  if (tid < 512) { vbh = Vb[h]; ubh = Ub[h]; wwh = ww[h]; }
  const float wb0 = wb[0];

  // ---- weights: bf16 B-fragments for this wave's K-quarter: 8 x uint4 = 32 VGPR ----
  // lane holds col o = nt*16 + l15; k = kq*256 + s*32 + kg*8 + i
  uint4 bfr[8];
  {
    const int o = (nt << 4) + l15;
    const float* Wr = (o < 32) ? (Vw + (size_t)o * NUM_IN) : (Uw + (size_t)(o - 32) * NUM_IN);
    #pragma unroll
    for (int s = 0; s < 8; ++s) {
      const int k0 = (kq << 8) + (s << 5) + (kg << 3);
      const float4 a = *reinterpret_cast<const float4*>(Wr + k0);
      const float4 c = *reinterpret_cast<const float4*>(Wr + k0 + 4);
      uint4 v;
      v.x = pk2(a.x, a.y); v.y = pk2(a.z, a.w);
      v.z = pk2(c.x, c.y); v.w = pk2(c.z, c.w);
      bfr[s] = v;
    }
    #pragma unroll
    for (int s = 0; s < 8; ++s)   // 32-bit tied anchors: keep weights resident
      asm volatile("" : "+v"(bfr[s].x), "+v"(bfr[s].y), "+v"(bfr[s].z), "+v"(bfr[s].w));
  }

  const float4* xg = reinterpret_cast<const float4*>(x);
  float4 stg[4];                  // 16 VGPR staging: thread's 4 float4 of a tile

  #define ISSUE(Tt) do { \
    _Pragma("unroll") \
    for (int j = 0; j < 4; ++j) stg[j] = xg[(size_t)(Tt) * T4 + (j << 10) + tid]; \
  } while (0)

  // convert staged f32 -> swizzled bf16 into buffer dst_ (thread's rows disjoint by tid)
  #define CONVERT(dst_) do { \
    char* xb_ = (char*)(dst_); \
    _Pragma("unroll") \
    for (int j = 0; j < 4; ++j) { \
      const int idx = (j << 10) + tid; \
      const int row = idx >> 8; \
      const int col8 = (idx & 255) << 3; \
      uint2 v; v.x = pk2(stg[j].x, stg[j].y); v.y = pk2(stg[j].z, stg[j].w); \
      *reinterpret_cast<uint2*>(xb_ + ((row << 11) + (col8 ^ ((row & 7) << 4)))) = v; \
    } \
  } while (0)

  float M = -INFINITY, S = 0.f;
  float aX = 0.f, aY = 0.f;
  int cur = 0;
  int T = b;

  // ---- prologue ----
  ISSUE(T);
  WAIT_VM0();
  CONVERT(xt[0]);
  if (T + nb < nTiles) ISSUE(T + nb);
  BARX();

  while (true) {
    const bool more1 = (T + nb)     < nTiles;
    const bool more2 = (T + 2 * nb) < nTiles;

    // ---- phase 1: MFMA partial logits for (nt, kq) on tile T ----
    {
      f32x4 acc = {0.f, 0.f, 0.f, 0.f};
      const char* xb = (const char*)xt[cur];
      #pragma unroll
      for (int s = 0; s < 8; ++s) {
        const int aoff = (l15 << 11) + ((((kq << 9) + (s << 6) + (kg << 4))) ^ ((l15 & 7) << 4));
        const bf16x8 af = *reinterpret_cast<const bf16x8*>(xb + aoff);
        acc = __builtin_amdgcn_mfma_f32_16x16x32_bf16(af, __builtin_bit_cast(bf16x8, bfr[s]), acc, 0, 0, 0);
      }
      #pragma unroll
      for (int r = 0; r < 4; ++r)
        prered[(kg << 2) + r][kq][(nt << 4) + l15] = acc[r];   // C/D: row=(l>>4)*4+r, col=l15
    }
    BARX();

    // ---- phase 2: waves 0-7 do activations+logits; waves 8-15 convert+issue ----
    if (tid >= 512) {
      if (more1) { WAIT_VM0(); CONVERT(xt[cur ^ 1]); if (more2) ISSUE(T + 2 * nb); }
    } else {
      float pv = vbh, pu = ubh;
      #pragma unroll
      for (int q = 0; q < 4; ++q) { pv += prered[rr][q][h]; pu += prered[rr][q][32 + h]; }
      const float ev = __expf(2.f * pv);
      const float av = (ev - 1.f) * __builtin_amdgcn_rcpf(ev + 1.f);   // tanh
      const float au = __builtin_amdgcn_rcpf(1.f + __expf(-pu));       // sigmoid
      float g = av * au * wwh;
      g += __shfl_xor(g, 1);
      g += __shfl_xor(g, 2);
      g += __shfl_xor(g, 4);
      g += __shfl_xor(g, 8);
      g += __shfl_xor(g, 16);
      if (h == 0) lgs[rr] = g + wb0;
    }
    BARX();

    // ---- phase 3: waves 0-7 convert+issue, then all do Phase B (own row-half) ----
    if (tid < 512 && more1) { WAIT_VM0(); CONVERT(xt[cur ^ 1]); if (more2) ISSUE(T + 2 * nb); }
    {
      float lf[8];
      #pragma unroll
      for (int j = 0; j < 8; ++j) lf[j] = lgs[r0 + j];
      float mc = lf[0];
      #pragma unroll
      for (int j = 1; j < 8; ++j) mc = fmaxf(mc, lf[j]);
      const float newM = fmaxf(M, mc);
      const float scale = __expf(M - newM);
      S *= scale; aX *= scale; aY *= scale;
      const char* xb = (const char*)xt[cur];
      #pragma unroll
      for (int j = 0; j < 8; ++j) {
        const int row = r0 + j;
        const float p = __expf(lf[j] - newM);
        S += p;
        const unsigned int xv = *reinterpret_cast<const unsigned int*>(
            xb + (row << 11) + (((c2 << 2)) ^ ((row & 7) << 4)));
        aX += p * bf2f(xv & 0xffffu);
        aY += p * bf2f(xv >> 16);
      }
      M = newM;
    }
    BARX();

    if (!more1) break;
    cur ^= 1;
    T += nb;
  }

  // ---- epilogue: merge the two row-halves (same cols) via LDS ----
  __syncthreads();
  float4* mg = reinterpret_cast<float4*>(&prered[0][0][0]);   // 1024 x float4 = 16 KB
  mg[tid] = make_float4(M, S, aX, aY);
  __syncthreads();
  if (hf == 0) {
    const float4 o = mg[tid + 512];
    const float Mf = fmaxf(M, o.x);
    const float e0 = __expf(M - Mf), e1 = __expf(o.x - Mf);
    const float Sf = S * e0 + o.y * e1;
    const float ax = aX * e0 + o.z * e1;
    const float ay = aY * e0 + o.w * e1;
    *reinterpret_cast<float2*>(&wsAcc[(size_t)b * NUM_IN + (c2 << 1)]) = make_float2(ax, ay);
    if (tid == 0) { wsM[b] = Mf; wsS[b] = Sf; }
  }
}

__global__ void ga_combine(const float* __restrict__ wsAcc, const float* __restrict__ wsM,
                           const float* __restrict__ wsS, float* __restrict__ out, int nb)
{
  const int e = blockIdx.x * blockDim.x + threadIdx.x;
  if (e >= NUM_IN) return;
  float M = -INFINITY;
  for (int i = 0; i < nb; ++i) M = fmaxf(M, wsM[i]);
  float S = 0.f, m = 0.f;
  for (int i = 0; i < nb; ++i) {
    const float wg = __expf(wsM[i] - M);
    S += wg * wsS[i];
    m = fmaf(wg, wsAcc[(size_t)i * NUM_IN + e], m);
  }
  out[e] = m / S;
}

extern "C" void kernel_launch(void* const* d_in, const int* in_sizes, int n_in,
                              void* d_out, int out_size, void* d_ws, size_t ws_size,
                              hipStream_t stream)
{
  const float* x  = (const float*)d_in[0];
  const float* Vw = (const float*)d_in[1];
  const float* Vb = (const float*)d_in[2];
  const float* Uw = (const float*)d_in[3];
  const float* Ub = (const float*)d_in[4];
  const float* ww = (const float*)d_in[5];
  const float* wb = (const float*)d_in[6];
  float* out = (float*)d_out;

  const int Nrows  = in_sizes[0] / NUM_IN;   // 200000
  const int nTiles = Nrows / TILE_R;         // 12500

  const size_t per = (size_t)NUM_IN * 4 + 8;
  int nb = (int)(ws_size / per);
  if (nb > NB_MAX)  nb = NB_MAX;
  if (nb > nTiles)  nb = nTiles;
  if (nb < 1)       nb = 1;

  float* wsAcc = (float*)d_ws;
  float* wsM   = wsAcc + (size_t)nb * NUM_IN;
  float* wsS   = wsM + nb;

  ga_main<<<nb, 1024, 0, stream>>>(x, Vw, Uw, Vb, Ub, ww, wb, wsAcc, wsM, wsS, nb, nTiles);
  ga_combine<<<4, 256, 0, stream>>>(wsAcc, wsM, wsS, out, nb);
}